// Round 6
// baseline (387.697 us; speedup 1.0000x reference)
//
#include <hip/hip_runtime.h>
#include <hip/hip_bf16.h>
#include <math.h>

typedef _Float16 half8 __attribute__((ext_vector_type(8)));
typedef float    f32x4 __attribute__((ext_vector_type(4)));

#define NPTS  50000
#define BATCH 8
#define PT 2          // point-row tiles per wave (32 rows/wave)

// ---------------- weight prep: fp32 -> f16, pi-permuted columns ----------------
// 8 slots of [128 rows o][128 positions pos]. pos=(ks,g,j):
//   k(pos) = ks*32 + 16*(j>>2) + 4*g + (j&3).
// Layer j's D-accumulator registers (after ELU+f16 pack) are directly the
// B-fragment of layer j+1 -- x never leaves registers (verified R2-R5).
// Slot 0: [pe60|pad4|z32|pad32]; 1..6: deform; 7: lin1a (3 rows used).
__global__ void prep_weights_k(const float* __restrict__ w_lin0,
                               const float* __restrict__ w_def,
                               const float* __restrict__ w1a,
                               _Float16* __restrict__ W)
{
    int idx = blockIdx.x * blockDim.x + threadIdx.x;
    if (idx >= 8*128*128) return;
    int slot = idx >> 14;
    int o    = (idx >> 7) & 127;
    int pos  = idx & 127;
    int ks = pos >> 5, l = pos & 31, gg = l >> 3, jj = l & 7;
    int k = ks*32 + 16*(jj>>2) + 4*gg + (jj&3);
    float v = 0.f;
    if (slot == 0) {
        if (k < 60)                 v = w_lin0[o*92 + k];
        else if (k >= 64 && k < 96) v = w_lin0[o*92 + 60 + (k-64)];
    } else if (slot <= 6) {
        v = w_def[(slot-1)*16384 + o*128 + k];
    } else {
        if (o < 3) v = w1a[o*128 + k];
    }
    W[idx] = (_Float16)v;
}

__device__ __forceinline__ float elu1(float v) {
    return (v > 0.f) ? v : (__expf(v) - 1.f);
}

// load one ft-PAIR of W panels (2 ft x 4 ks = 8 x 16B per lane)
__device__ __forceinline__ void load_pair(half8 (&dst)[8],
                                          const unsigned char* __restrict__ base,
                                          int voff)
{
    #pragma unroll
    for (int f = 0; f < 2; ++f)
        #pragma unroll
        for (int ks = 0; ks < 4; ++ks)
            dst[f*4+ks] = *(const half8*)(base + voff + f*4096 + ks*64);
}

// ---- one layer = 4 ft-pairs. Pair-level A double-buffer (A[2][8] = 64 VGPR),
// prefetching pair p+1 (or the NEXT layer's pair 0) before pair p's MFMAs --
// ~200+ cycles of independent work covers the L2 load latency. Pack (ELU+cvt)
// of pair p feeds Bout ks-slot p. Entry/exit invariant: pair0 of the current/
// next layer sits in A[0].
template<int NKS, bool DOELU>
__device__ __forceinline__ void layer_step(const unsigned char* __restrict__ Wl,
                                           const unsigned char* __restrict__ Wnext,
                                           const half8 (&Bin)[PT][4],
                                           half8 (&Bout)[PT][4],
                                           half8 (&A)[2][8],
                                           int voff)
{
    const f32x4 Z = {0.f, 0.f, 0.f, 0.f};
    #pragma unroll
    for (int pr = 0; pr < 4; ++pr) {
        const int cur = pr & 1, nxt = cur ^ 1;
        if (pr < 3) load_pair(A[nxt], Wl + 2*(pr+1)*4096, voff);
        else        load_pair(A[nxt], Wnext, voff);

        f32x4 acc[PT][2];
        #pragma unroll
        for (int f = 0; f < 2; ++f)
            #pragma unroll
            for (int pt = 0; pt < PT; ++pt) {
                acc[pt][f] = __builtin_amdgcn_mfma_f32_16x16x32_f16(
                    A[cur][f*4+0], Bin[pt][0], Z, 0, 0, 0);
                #pragma unroll
                for (int ks = 1; ks < NKS; ++ks)
                    acc[pt][f] = __builtin_amdgcn_mfma_f32_16x16x32_f16(
                        A[cur][f*4+ks], Bin[pt][ks], acc[pt][f], 0, 0, 0);
            }
        #pragma unroll
        for (int pt = 0; pt < PT; ++pt) {
            half8 h;
            #pragma unroll
            for (int q = 0; q < 4; ++q) {
                float v0 = acc[pt][0][q];
                float v1 = acc[pt][1][q];
                if (DOELU) { v0 = elu1(v0); v1 = elu1(v1); }
                h[q]   = (_Float16)v0;
                h[4+q] = (_Float16)v1;
            }
            Bout[pt][pr] = h;
        }
    }
}

// ---------------- fused decoder: no LDS, no barriers, 3 waves/SIMD ----------------
// Each wave: 32 rows (4 n x 8 b), all 128 features in registers end-to-end.
// W read straight from L2 (256 KB, resident -- FETCH_SIZE confirms).
__global__ __launch_bounds__(256, 3)
void decoder_main(const float* __restrict__ z0,
                  const float* __restrict__ cons,
                  const _Float16* __restrict__ W,
                  const float* __restrict__ w1b,
                  float* __restrict__ out)
{
    const int lane = threadIdx.x & 63;
    const int wid  = threadIdx.x >> 6;
    const int p = lane & 15;
    const int g = lane >> 4;
    const int n0 = blockIdx.x * 16 + wid * 4;   // 3125 blocks * 16 n = 50000 exactly
    const int voff = p*256 + g*16;

    const f32x4 Z = {0.f, 0.f, 0.f, 0.f};
    const unsigned char* Wb = (const unsigned char*)W;

    // ---- issue layer-0 pair-0 loads first; posenc VALU below covers them ----
    half8 A[2][8];
    load_pair(A[0], Wb, voff);

    // ---- build layer-0 B-fragments (pi-position order), K=96 -> ks 0..2 ----
    half8 B1[PT][4], B2[PT][4];
    #pragma unroll
    for (int pt = 0; pt < PT; ++pt) {
        const int lrow = pt*16 + p;
        const int n = n0 + (lrow >> 3);
        const int b = lrow & 7;
        float c0 = cons[n*3+0], c1 = cons[n*3+1], c2 = cons[n*3+2];
        #pragma unroll
        for (int ks = 0; ks < 2; ++ks) {
            half8 h;
            #pragma unroll
            for (int j = 0; j < 8; ++j) {
                int k = ks*32 + 16*(j>>2) + 4*g + (j&3);
                float v = 0.f;
                if (k < 60) {
                    int c = k/20, rem = k%20, i = rem%10;
                    float f  = exp2f(7.f * (1.f - (float)i * (1.f/9.f)));  // const-folded
                    float cc = (c == 0) ? c0 : (c == 1) ? c1 : c2;
                    float a  = cc * f;
                    v = (rem < 10) ? __sinf(a) : __cosf(a);
                }
                h[j] = (_Float16)v;
            }
            B1[pt][ks] = h;
        }
        half8 hz;
        #pragma unroll
        for (int j = 0; j < 8; ++j)
            hz[j] = (_Float16)z0[b*32 + 16*(j>>2) + 4*g + (j&3)];
        B1[pt][2] = hz;
    }

    // ---- 7 layers, software-pipelined A prefetch across layer boundaries ----
    layer_step<3, false>(Wb,           Wb + 1*32768, B1, B2, A, voff);  // lin0 K=96
    layer_step<4, true >(Wb + 1*32768, Wb + 2*32768, B2, B1, A, voff);
    layer_step<4, true >(Wb + 2*32768, Wb + 3*32768, B1, B2, A, voff);
    layer_step<4, true >(Wb + 3*32768, Wb + 4*32768, B2, B1, A, voff);
    layer_step<4, true >(Wb + 4*32768, Wb + 5*32768, B1, B2, A, voff);
    layer_step<4, true >(Wb + 5*32768, Wb + 6*32768, B2, B1, A, voff);
    layer_step<4, true >(Wb + 6*32768, Wb + 7*32768, B1, B2, A, voff);  // prefetches lin1a
    // final activations in B2; lin1a panels (slot 7, ft=0) already in A[0][0..3]

    // ---- lin1a: 16 output rows (3 used), K=128 ----
    f32x4 a1[PT];
    {
        #pragma unroll
        for (int pt = 0; pt < PT; ++pt)
            a1[pt] = __builtin_amdgcn_mfma_f32_16x16x32_f16(A[0][0], B2[pt][0], Z, 0, 0, 0);
        #pragma unroll
        for (int ks = 1; ks < 4; ++ks)
            #pragma unroll
            for (int pt = 0; pt < PT; ++pt)
                a1[pt] = __builtin_amdgcn_mfma_f32_16x16x32_f16(A[0][ks], B2[pt][ks], a1[pt], 0, 0, 0);
    }

    // ---- ELU + lin1b (3x3) + stores, in-register (g==0 lanes own feats 0..3) ----
    if (g == 0) {
        float b00=w1b[0],b01=w1b[1],b02=w1b[2];
        float b10=w1b[3],b11=w1b[4],b12=w1b[5];
        float b20=w1b[6],b21=w1b[7],b22=w1b[8];
        #pragma unroll
        for (int pt = 0; pt < PT; ++pt) {
            int row = pt*16 + p;
            int n = n0 + (row >> 3);
            int b = row & 7;
            float r0 = elu1(a1[pt][0]);
            float r1 = elu1(a1[pt][1]);
            float r2 = elu1(a1[pt][2]);
            int obase = (b*NPTS + n)*3;
            float rv0 = b00*r0 + b01*r1 + b02*r2;
            float rv1 = b10*r0 + b11*r1 + b12*r2;
            float rv2 = b20*r0 + b21*r1 + b22*r2;
            out[obase+0] = cons[n*3+0] + rv0;
            out[obase+1] = cons[n*3+1] + rv1;
            out[obase+2] = cons[n*3+2] + rv2;
            out[BATCH*NPTS*3 + obase+0] = rv0;
            out[BATCH*NPTS*3 + obase+1] = rv1;
            out[BATCH*NPTS*3 + obase+2] = rv2;
        }
    }
}

extern "C" void kernel_launch(void* const* d_in, const int* in_sizes, int n_in,
                              void* d_out, int out_size, void* d_ws, size_t ws_size,
                              hipStream_t stream)
{
    const float* z0     = (const float*)d_in[0];
    const float* cons   = (const float*)d_in[1];
    const float* w_lin0 = (const float*)d_in[2];
    const float* w_def  = (const float*)d_in[3];
    const float* w1a    = (const float*)d_in[4];
    const float* w1b    = (const float*)d_in[5];
    _Float16* W = (_Float16*)d_ws;   // 8 slots * 16384 f16 = 256 KB

    prep_weights_k<<<512, 256, 0, stream>>>(w_lin0, w_def, w1a, W);
    decoder_main<<<NPTS/16, 256, 0, stream>>>(z0, cons, W, w1b, (float*)d_out);
}

// Round 8
// 182.451 us; speedup vs baseline: 2.1249x; 2.1249x over previous
//
#include <hip/hip_runtime.h>
#include <hip/hip_bf16.h>
#include <math.h>

typedef _Float16 half8 __attribute__((ext_vector_type(8)));
typedef float    f32x4 __attribute__((ext_vector_type(4)));

#define NPTS  50000
#define BATCH 8
#define PT 2          // point-row tiles per wave (32 rows/wave)

// ---------------- weight prep: fp32 -> f16, FRAGMENT-ORDER layout ----------------
// Flat layout: f16 index = slot*16384 + ft*2048 + ks*512 + lane*8 + j
// holding element W[o = ft*16 + (lane&15)][k = ks*32 + 16*(j>>2) + 4*(lane>>4) + (j&3)].
// => each (ft,ks) panel is a contiguous 1KB chunk; a wave's A-load is
// global_load_dwordx4 at base + lane*16: ONE coalesced segment (was a
// 16-segment gather -- the R3-R6 TA bottleneck).
// pi column permutation unchanged: layer j's D-acc registers (after ELU+pack)
// are directly layer j+1's B-fragment (verified R2-R6).
// Slot 0: [pe60|pad4|z32|pad32]; 1..6: deform; 7: lin1a (3 rows used).
__global__ void prep_weights_k(const float* __restrict__ w_lin0,
                               const float* __restrict__ w_def,
                               const float* __restrict__ w1a,
                               _Float16* __restrict__ W)
{
    int idx = blockIdx.x * blockDim.x + threadIdx.x;
    if (idx >= 8*128*128) return;
    int slot = idx >> 14;
    int r    = idx & 16383;
    int ft   = r >> 11;
    int ks   = (r >> 9) & 3;
    int lane = (r >> 3) & 63;
    int j    = r & 7;
    int p = lane & 15, g = lane >> 4;
    int o = ft*16 + p;
    int k = ks*32 + 16*(j>>2) + 4*g + (j&3);
    float v = 0.f;
    if (slot == 0) {
        if (k < 60)                 v = w_lin0[o*92 + k];
        else if (k >= 64 && k < 96) v = w_lin0[o*92 + 60 + (k-64)];
    } else if (slot <= 6) {
        v = w_def[(slot-1)*16384 + o*128 + k];
    } else {
        if (o < 3) v = w1a[o*128 + k];
    }
    W[idx] = (_Float16)v;
}

__device__ __forceinline__ float elu1(float v) {
    return (v > 0.f) ? v : (__expf(v) - 1.f);
}

// ---- one layer = 8 ft phases. A double-buffered at ft level (A[2][4]).
// acc PING-PONG at pair level (acc[2][PT][2]): pack of pair pr-1 (other acc
// set) is issued between pair pr's MFMAs -- no WAR chain, MFMA/VALU overlap
// within the wave. Entry invariant: A[0] = this layer's ft0 panels.
// Exit: A[0] = next layer's (Wnext) ft0 panels.
template<int NKS, bool DOELU>
__device__ __forceinline__ void layer_step(const unsigned char* __restrict__ Wl,
                                           const unsigned char* __restrict__ Wnext,
                                           const half8 (&Bin)[PT][4],
                                           half8 (&Bout)[PT][4],
                                           half8 (&A)[2][4],
                                           int voff)
{
    const f32x4 Z = {0.f, 0.f, 0.f, 0.f};
    f32x4 acc[2][PT][2];
    #pragma unroll
    for (int ft = 0; ft < 8; ++ft) {
        const int cur = ft & 1, nxt = cur ^ 1;
        const unsigned char* pbase = (ft < 7) ? (Wl + (ft+1)*4096) : Wnext;
        #pragma unroll
        for (int ks = 0; ks < 4; ++ks)
            A[nxt][ks] = *(const half8*)(pbase + voff + ks*1024);

        const int pr = ft >> 1;     // pair index
        const int as = pr & 1;      // acc set for this pair
        const int f  = ft & 1;
        #pragma unroll
        for (int pt = 0; pt < PT; ++pt) {
            f32x4 a = __builtin_amdgcn_mfma_f32_16x16x32_f16(
                A[cur][0], Bin[pt][0], Z, 0, 0, 0);
            #pragma unroll
            for (int ks = 1; ks < NKS; ++ks)
                a = __builtin_amdgcn_mfma_f32_16x16x32_f16(
                    A[cur][ks], Bin[pt][ks], a, 0, 0, 0);
            acc[as][pt][f] = a;
        }
        if (f == 0 && pr >= 1) {
            // pack pair pr-1 (acc set as^1) while pair pr's MFMAs run
            #pragma unroll
            for (int pt = 0; pt < PT; ++pt) {
                half8 h;
                #pragma unroll
                for (int q = 0; q < 4; ++q) {
                    float v0 = acc[as^1][pt][0][q];
                    float v1 = acc[as^1][pt][1][q];
                    if (DOELU) { v0 = elu1(v0); v1 = elu1(v1); }
                    h[q]   = (_Float16)v0;
                    h[4+q] = (_Float16)v1;
                }
                Bout[pt][pr-1] = h;
            }
        }
    }
    // tail: pack pair 3 (acc set 1)
    #pragma unroll
    for (int pt = 0; pt < PT; ++pt) {
        half8 h;
        #pragma unroll
        for (int q = 0; q < 4; ++q) {
            float v0 = acc[1][pt][0][q];
            float v1 = acc[1][pt][1][q];
            if (DOELU) { v0 = elu1(v0); v1 = elu1(v1); }
            h[q]   = (_Float16)v0;
            h[4+q] = (_Float16)v1;
        }
        Bout[pt][3] = h;
    }
}

// ---------------- fused decoder: no LDS, no barriers, 3 waves/SIMD ----------------
// Each wave: 32 rows (4 n x 8 b), all 128 features in registers end-to-end.
// W read straight from L1/L2 with fully-coalesced 1KB fragment loads.
__global__ __launch_bounds__(256, 3)
void decoder_main(const float* __restrict__ z0,
                  const float* __restrict__ cons,
                  const _Float16* __restrict__ W,
                  const float* __restrict__ w1b,
                  float* __restrict__ out)
{
    const int lane = threadIdx.x & 63;
    const int wid  = threadIdx.x >> 6;
    const int p = lane & 15;
    const int g = lane >> 4;
    const int n0 = blockIdx.x * 16 + wid * 4;   // 3125 blocks * 16 n = 50000 exactly
    const int voff = lane * 16;                 // coalesced fragment offset

    const f32x4 Z = {0.f, 0.f, 0.f, 0.f};
    const unsigned char* Wb = (const unsigned char*)W;

    // ---- issue layer-0 ft0 loads first; posenc VALU below covers the latency ----
    half8 A[2][4];
    #pragma unroll
    for (int ks = 0; ks < 4; ++ks)
        A[0][ks] = *(const half8*)(Wb + voff + ks*1024);

    // ---- build layer-0 B-fragments (pi-position order), K=96 -> ks 0..2 ----
    half8 B1[PT][4], B2[PT][4];
    #pragma unroll
    for (int pt = 0; pt < PT; ++pt) {
        const int lrow = pt*16 + p;
        const int n = n0 + (lrow >> 3);
        const int b = lrow & 7;
        float c0 = cons[n*3+0], c1 = cons[n*3+1], c2 = cons[n*3+2];
        #pragma unroll
        for (int ks = 0; ks < 2; ++ks) {
            half8 h;
            #pragma unroll
            for (int j = 0; j < 8; ++j) {
                int k = ks*32 + 16*(j>>2) + 4*g + (j&3);
                float v = 0.f;
                if (k < 60) {
                    int c = k/20, rem = k%20, i = rem%10;
                    float f  = exp2f(7.f * (1.f - (float)i * (1.f/9.f)));  // const-folded
                    float cc = (c == 0) ? c0 : (c == 1) ? c1 : c2;
                    float a  = cc * f;
                    v = (rem < 10) ? __sinf(a) : __cosf(a);
                }
                h[j] = (_Float16)v;
            }
            B1[pt][ks] = h;
        }
        half8 hz;
        #pragma unroll
        for (int j = 0; j < 8; ++j)
            hz[j] = (_Float16)z0[b*32 + 16*(j>>2) + 4*g + (j&3)];
        B1[pt][2] = hz;
    }

    // ---- 7 layers, A prefetch pipelined across layer boundaries ----
    layer_step<3, false>(Wb,           Wb + 1*32768, B1, B2, A, voff);  // lin0 K=96
    layer_step<4, true >(Wb + 1*32768, Wb + 2*32768, B2, B1, A, voff);
    layer_step<4, true >(Wb + 2*32768, Wb + 3*32768, B1, B2, A, voff);
    layer_step<4, true >(Wb + 3*32768, Wb + 4*32768, B2, B1, A, voff);
    layer_step<4, true >(Wb + 4*32768, Wb + 5*32768, B1, B2, A, voff);
    layer_step<4, true >(Wb + 5*32768, Wb + 6*32768, B2, B1, A, voff);
    layer_step<4, true >(Wb + 6*32768, Wb + 7*32768, B1, B2, A, voff);  // prefetches lin1a
    // final activations in B2; lin1a ft0 panels already in A[0]

    // ---- lin1a: 16 output rows (3 used), K=128 ----
    f32x4 a1[PT];
    {
        #pragma unroll
        for (int pt = 0; pt < PT; ++pt)
            a1[pt] = __builtin_amdgcn_mfma_f32_16x16x32_f16(A[0][0], B2[pt][0], Z, 0, 0, 0);
        #pragma unroll
        for (int ks = 1; ks < 4; ++ks)
            #pragma unroll
            for (int pt = 0; pt < PT; ++pt)
                a1[pt] = __builtin_amdgcn_mfma_f32_16x16x32_f16(A[0][ks], B2[pt][ks], a1[pt], 0, 0, 0);
    }

    // ---- ELU + lin1b (3x3) + stores, in-register (g==0 lanes own feats 0..3) ----
    if (g == 0) {
        float b00=w1b[0],b01=w1b[1],b02=w1b[2];
        float b10=w1b[3],b11=w1b[4],b12=w1b[5];
        float b20=w1b[6],b21=w1b[7],b22=w1b[8];
        #pragma unroll
        for (int pt = 0; pt < PT; ++pt) {
            int row = pt*16 + p;
            int n = n0 + (row >> 3);
            int b = row & 7;
            float r0 = elu1(a1[pt][0]);
            float r1 = elu1(a1[pt][1]);
            float r2 = elu1(a1[pt][2]);
            int obase = (b*NPTS + n)*3;
            float rv0 = b00*r0 + b01*r1 + b02*r2;
            float rv1 = b10*r0 + b11*r1 + b12*r2;
            float rv2 = b20*r0 + b21*r1 + b22*r2;
            out[obase+0] = cons[n*3+0] + rv0;
            out[obase+1] = cons[n*3+1] + rv1;
            out[obase+2] = cons[n*3+2] + rv2;
            out[BATCH*NPTS*3 + obase+0] = rv0;
            out[BATCH*NPTS*3 + obase+1] = rv1;
            out[BATCH*NPTS*3 + obase+2] = rv2;
        }
    }
}

extern "C" void kernel_launch(void* const* d_in, const int* in_sizes, int n_in,
                              void* d_out, int out_size, void* d_ws, size_t ws_size,
                              hipStream_t stream)
{
    const float* z0     = (const float*)d_in[0];
    const float* cons   = (const float*)d_in[1];
    const float* w_lin0 = (const float*)d_in[2];
    const float* w_def  = (const float*)d_in[3];
    const float* w1a    = (const float*)d_in[4];
    const float* w1b    = (const float*)d_in[5];
    _Float16* W = (_Float16*)d_ws;   // 8 slots * 16384 f16 = 256 KB

    prep_weights_k<<<512, 256, 0, stream>>>(w_lin0, w_def, w1a, W);
    decoder_main<<<NPTS/16, 256, 0, stream>>>(z0, cons, W, w1b, (float*)d_out);
}

// Round 10
// 176.112 us; speedup vs baseline: 2.2014x; 1.0360x over previous
//
#include <hip/hip_runtime.h>
#include <hip/hip_bf16.h>
#include <math.h>

typedef _Float16 half8  __attribute__((ext_vector_type(8)));
typedef float    f32x4  __attribute__((ext_vector_type(4)));

#define NPTS  50000
#define BATCH 8
#define PT 2          // point-row tiles per wave (32 rows/wave)

// ---------------- weight prep: fp32 -> f16, FRAGMENT-ORDER layout ----------------
// f16 index = slot*16384 + ft*2048 + ks*512 + lane*8 + j
// holds W[o = ft*16 + (lane&15)][k = ks*32 + 16*(j>>2) + 4*(lane>>4) + (j&3)].
// Each (ft,ks) panel is a contiguous 1KB chunk -> a wave's A-load is one
// coalesced segment (R8: 343->128us). pi column permutation: layer j's D-acc
// (after ELU+pack) is directly layer j+1's B-fragment (verified R2-R8).
// Slot 0: [pe60|pad4|z32|pad32]; 1..6: deform; 7: lin1a (3 rows used).
// Appendix at +8*16384: z0 pre-permuted to fragment order (8 b x 32 f16).
__global__ void prep_weights_k(const float* __restrict__ w_lin0,
                               const float* __restrict__ w_def,
                               const float* __restrict__ w1a,
                               const float* __restrict__ z0,
                               _Float16* __restrict__ W)
{
    int idx = blockIdx.x * blockDim.x + threadIdx.x;
    if (idx < 8*128*128) {
        int slot = idx >> 14;
        int r    = idx & 16383;
        int ft   = r >> 11;
        int ks   = (r >> 9) & 3;
        int lane = (r >> 3) & 63;
        int j    = r & 7;
        int p = lane & 15, g = lane >> 4;
        int o = ft*16 + p;
        int k = ks*32 + 16*(j>>2) + 4*g + (j&3);
        float v = 0.f;
        if (slot == 0) {
            if (k < 60)                 v = w_lin0[o*92 + k];
            else if (k >= 64 && k < 96) v = w_lin0[o*92 + 60 + (k-64)];
        } else if (slot <= 6) {
            v = w_def[(slot-1)*16384 + o*128 + k];
        } else {
            if (o < 3) v = w1a[o*128 + k];
        }
        W[idx] = (_Float16)v;
    } else if (idx < 8*128*128 + 256) {
        int zi = idx - 8*128*128;
        int b = zi >> 5, pos = zi & 31, g = pos >> 3, j = pos & 7;
        W[8*16384 + b*32 + pos] = (_Float16)z0[b*32 + 16*(j>>2) + 4*g + (j&3)];
    }
}

__device__ __forceinline__ float elu1(float v) {
    return (v > 0.f) ? v : (__expf(v) - 1.f);
}

// ELU (f32) + packed f16 convert. v_cvt_pkrtz_f16_f32 via inline asm (the
// builtin's return type fails template substitution on this toolchain);
// 4 pack instructions replace 8 cvt + 4 pack-shift.
template<bool DOELU>
__device__ __forceinline__ half8 pack_pair(f32x4 e, f32x4 o) {
    if (DOELU) {
        #pragma unroll
        for (int q = 0; q < 4; ++q) { e[q] = elu1(e[q]); o[q] = elu1(o[q]); }
    }
    union { half8 h; unsigned int u[4]; } u;
    asm("v_cvt_pkrtz_f16_f32 %0, %1, %2" : "=v"(u.u[0]) : "v"(e[0]), "v"(e[1]));
    asm("v_cvt_pkrtz_f16_f32 %0, %1, %2" : "=v"(u.u[1]) : "v"(e[2]), "v"(e[3]));
    asm("v_cvt_pkrtz_f16_f32 %0, %1, %2" : "=v"(u.u[2]) : "v"(o[0]), "v"(o[1]));
    asm("v_cvt_pkrtz_f16_f32 %0, %1, %2" : "=v"(u.u[3]) : "v"(o[2]), "v"(o[3]));
    return u.h;
}

// ---- one layer = 8 ft phases. A ring-of-3 (2 ft-panels in flight: ~160cyc
// own-wave latency cover, ~480 with 3-wave TLP, vs ~200cyc L1/L2 latency).
// Ring rotates by 8%3=2 per layer -> template R tracks the rotation statically.
// acc ping-pong at pair level: pack of pair pr-1 issues between pair pr's
// MFMAs (no WAR chain). setprio(1) around MFMA chains (T5, independent waves).
// Entry: A[R]=ft0, A[(R+1)%3]=ft1. Exit: same invariant for Wnext with R'=(R+2)%3.
template<int NKS, bool DOELU, int R>
__device__ __forceinline__ void layer_step(const unsigned char* __restrict__ Wl,
                                           const unsigned char* __restrict__ Wnext,
                                           const half8 (&Bin)[PT][4],
                                           half8 (&Bout)[PT][4],
                                           half8 (&A)[3][4],
                                           int voff)
{
    const f32x4 Z = {0.f, 0.f, 0.f, 0.f};
    f32x4 acc[2][PT][2];
    #pragma unroll
    for (int ft = 0; ft < 8; ++ft) {
        const int cur = (R + ft) % 3;
        const int pf  = (R + ft + 2) % 3;
        const unsigned char* pbase = (ft < 6) ? (Wl + (ft+2)*4096)
                                              : (Wnext + (ft-6)*4096);
        #pragma unroll
        for (int ks = 0; ks < 4; ++ks)
            A[pf][ks] = *(const half8*)(pbase + voff + ks*1024);

        const int pr = ft >> 1, as = pr & 1, f = ft & 1;
        __builtin_amdgcn_s_setprio(1);
        #pragma unroll
        for (int pt = 0; pt < PT; ++pt) {
            f32x4 a = __builtin_amdgcn_mfma_f32_16x16x32_f16(
                A[cur][0], Bin[pt][0], Z, 0, 0, 0);
            #pragma unroll
            for (int ks = 1; ks < NKS; ++ks)
                a = __builtin_amdgcn_mfma_f32_16x16x32_f16(
                    A[cur][ks], Bin[pt][ks], a, 0, 0, 0);
            acc[as][pt][f] = a;
        }
        __builtin_amdgcn_s_setprio(0);
        if (f == 0 && pr >= 1) {   // pack pair pr-1 while pair pr's MFMAs run
            #pragma unroll
            for (int pt = 0; pt < PT; ++pt)
                Bout[pt][pr-1] = pack_pair<DOELU>(acc[as^1][pt][0], acc[as^1][pt][1]);
        }
    }
    #pragma unroll
    for (int pt = 0; pt < PT; ++pt)   // tail: pack pair 3
        Bout[pt][3] = pack_pair<DOELU>(acc[1][pt][0], acc[1][pt][1]);
}

// ---------------- fused decoder: no LDS, no barriers, 3 waves/SIMD ----------------
// Each wave: 32 rows (4 n x 8 b), all 128 features in registers end-to-end.
__global__ __launch_bounds__(256, 3)
void decoder_main(const float* __restrict__ z0,
                  const float* __restrict__ cons,
                  const _Float16* __restrict__ W,
                  const float* __restrict__ w1b,
                  float* __restrict__ out)
{
    const int lane = threadIdx.x & 63;
    const int wid  = threadIdx.x >> 6;
    const int p = lane & 15;
    const int g = lane >> 4;
    const int n0 = blockIdx.x * 16 + wid * 4;   // 3125 blocks * 16 n = 50000 exactly
    const int voff = lane * 16;                 // coalesced fragment offset

    const f32x4 Z = {0.f, 0.f, 0.f, 0.f};
    const unsigned char* Wb = (const unsigned char*)W;

    // ---- issue layer-0 ft0+ft1 loads first; posenc VALU covers the latency ----
    half8 A[3][4];
    #pragma unroll
    for (int ks = 0; ks < 4; ++ks) {
        A[0][ks] = *(const half8*)(Wb + voff + ks*1024);
        A[1][ks] = *(const half8*)(Wb + 4096 + voff + ks*1024);
    }

    // ---- build layer-0 B-fragments (pi order), K=96 -> ks 0..2 ----
    half8 B1[PT][4], B2[PT][4];
    {   // z fragment: b = (pt*16+p)&7 = p&7, identical for both pt
        const unsigned char* zt = (const unsigned char*)(W + 8*16384);
        half8 hz = *(const half8*)(zt + (p & 7)*64 + g*16);
        B1[0][2] = hz;
        B1[1][2] = hz;
    }
    #pragma unroll
    for (int pt = 0; pt < PT; ++pt) {
        const int lrow = pt*16 + p;
        const int n = n0 + (lrow >> 3);
        float c0 = cons[n*3+0], c1 = cons[n*3+1], c2 = cons[n*3+2];
        #pragma unroll
        for (int ks = 0; ks < 2; ++ks) {
            half8 h;
            #pragma unroll
            for (int j = 0; j < 8; ++j) {
                int k = ks*32 + 16*(j>>2) + 4*g + (j&3);
                float v = 0.f;
                if (k < 60) {
                    int c = k/20, rem = k%20, i = rem%10;
                    float f  = exp2f(7.f * (1.f - (float)i * (1.f/9.f)));  // const-folded
                    float cc = (c == 0) ? c0 : (c == 1) ? c1 : c2;
                    float a  = cc * f;
                    v = (rem < 10) ? __sinf(a) : __cosf(a);
                }
                h[j] = (_Float16)v;
            }
            B1[pt][ks] = h;
        }
    }

    // ---- 7 layers; ring rotation R: 0,2,1,0,2,1,0 ----
    layer_step<3, false, 0>(Wb,           Wb + 1*32768, B1, B2, A, voff);  // lin0 K=96
    layer_step<4, true,  2>(Wb + 1*32768, Wb + 2*32768, B2, B1, A, voff);
    layer_step<4, true,  1>(Wb + 2*32768, Wb + 3*32768, B1, B2, A, voff);
    layer_step<4, true,  0>(Wb + 3*32768, Wb + 4*32768, B2, B1, A, voff);
    layer_step<4, true,  2>(Wb + 4*32768, Wb + 5*32768, B1, B2, A, voff);
    layer_step<4, true,  1>(Wb + 5*32768, Wb + 6*32768, B2, B1, A, voff);
    layer_step<4, true,  0>(Wb + 6*32768, Wb + 7*32768, B1, B2, A, voff);
    // final activations in B2; lin1a (slot7) ft0 panels in A[2]

    // ---- lin1a: 16 output rows (3 used), K=128 ----
    f32x4 a1[PT];
    {
        #pragma unroll
        for (int pt = 0; pt < PT; ++pt)
            a1[pt] = __builtin_amdgcn_mfma_f32_16x16x32_f16(A[2][0], B2[pt][0], Z, 0, 0, 0);
        #pragma unroll
        for (int ks = 1; ks < 4; ++ks)
            #pragma unroll
            for (int pt = 0; pt < PT; ++pt)
                a1[pt] = __builtin_amdgcn_mfma_f32_16x16x32_f16(A[2][ks], B2[pt][ks], a1[pt], 0, 0, 0);
    }

    // ---- ELU + lin1b (3x3) + stores (g==0 lanes own feats 0..3) ----
    if (g == 0) {
        float b00=w1b[0],b01=w1b[1],b02=w1b[2];
        float b10=w1b[3],b11=w1b[4],b12=w1b[5];
        float b20=w1b[6],b21=w1b[7],b22=w1b[8];
        #pragma unroll
        for (int pt = 0; pt < PT; ++pt) {
            int row = pt*16 + p;
            int n = n0 + (row >> 3);
            int b = row & 7;
            float r0 = elu1(a1[pt][0]);
            float r1 = elu1(a1[pt][1]);
            float r2 = elu1(a1[pt][2]);
            int obase = (b*NPTS + n)*3;
            float rv0 = b00*r0 + b01*r1 + b02*r2;
            float rv1 = b10*r0 + b11*r1 + b12*r2;
            float rv2 = b20*r0 + b21*r1 + b22*r2;
            out[obase+0] = cons[n*3+0] + rv0;
            out[obase+1] = cons[n*3+1] + rv1;
            out[obase+2] = cons[n*3+2] + rv2;
            out[BATCH*NPTS*3 + obase+0] = rv0;
            out[BATCH*NPTS*3 + obase+1] = rv1;
            out[BATCH*NPTS*3 + obase+2] = rv2;
        }
    }
}

extern "C" void kernel_launch(void* const* d_in, const int* in_sizes, int n_in,
                              void* d_out, int out_size, void* d_ws, size_t ws_size,
                              hipStream_t stream)
{
    const float* z0     = (const float*)d_in[0];
    const float* cons   = (const float*)d_in[1];
    const float* w_lin0 = (const float*)d_in[2];
    const float* w_def  = (const float*)d_in[3];
    const float* w1a    = (const float*)d_in[4];
    const float* w1b    = (const float*)d_in[5];
    _Float16* W = (_Float16*)d_ws;   // 8 slots * 16384 f16 + 256 f16 z-table

    prep_weights_k<<<513, 256, 0, stream>>>(w_lin0, w_def, w1a, z0, W);
    decoder_main<<<NPTS/16, 256, 0, stream>>>(z0, cons, W, w1b, (float*)d_out);
}